// Round 1
// baseline (1075.428 us; speedup 1.0000x reference)
//
#include <hip/hip_runtime.h>

#define N_   150
#define P_   16
#define HID_ 50
#define H2_  25
#define DE_  14
#define DO_  10
#define NT_  5
#define EPR  149          // edges per receiver (N-1)
#define RPB  3            // receivers per block (150 = 3*50)
#define TPB_A 448         // 3*149 = 447 edge threads + 1 pad (7 waves)
#define B_   256

// ---------------------------------------------------------------------------
// Kernel A: edge MLP (fr1/fr2/fr3) + per-receiver aggregation + object MLP
// (fo1/fo2/fo3), fused. One block = (batch b, 3 consecutive receivers).
// Edges are receiver-sorted in the input, so aggregation needs only LDS adds.
// Writes O[b, n*DO + d] (the classifier's flat input layout).
// ---------------------------------------------------------------------------
__global__ __launch_bounds__(TPB_A) void edge_obj_kernel(
    const float* __restrict__ x, const int* __restrict__ send,
    const float* __restrict__ fr1_w, const float* __restrict__ fr1_b,
    const float* __restrict__ fr2_w, const float* __restrict__ fr2_b,
    const float* __restrict__ fr3_w, const float* __restrict__ fr3_b,
    const float* __restrict__ fo1_w, const float* __restrict__ fo1_b,
    const float* __restrict__ fo2_w, const float* __restrict__ fo2_b,
    const float* __restrict__ fo3_w, const float* __restrict__ fo3_b,
    float* __restrict__ O)
{
    __shared__ float s_x[RPB][P_];      // receiver columns of x
    __shared__ float s_eacc[RPB][DE_];  // Ebar accumulator
    __shared__ float s_h1[RPB][HID_];
    __shared__ float s_h2[RPB][H2_];

    const int b  = blockIdx.x / (N_ / RPB);
    const int r0 = (blockIdx.x % (N_ / RPB)) * RPB;
    const int t  = threadIdx.x;
    const int xbase = b * (P_ * N_);

    if (t < RPB * P_) {
        int q = t / P_, p = t % P_;
        s_x[q][p] = x[xbase + p * N_ + (r0 + q)];
    }
    if (t < RPB * DE_) {
        s_eacc[t / DE_][t % DE_] = 0.0f;
    }
    __syncthreads();

    if (t < RPB * EPR) {
        const int q = t / EPR;
        const int j = t - q * EPR;
        const int r = r0 + q;
        const int s = send[r * EPR + j];   // coalesced: global edge = r0*EPR + t

        float xr[P_], xs[P_];
#pragma unroll
        for (int p = 0; p < P_; ++p) xr[p] = s_x[q][p];
#pragma unroll
        for (int p = 0; p < P_; ++p) xs[p] = x[xbase + p * N_ + s];

        // fr1: 32 -> 50   (weights: uniform addr -> s_load; 2 acc chains for ILP)
        float h1[HID_];
#pragma unroll
        for (int i = 0; i < HID_; ++i) {
            float a0 = fr1_b[i], a1 = 0.0f;
#pragma unroll
            for (int p = 0; p < P_; ++p) {
                a0 = fmaf(fr1_w[i * 32 + p],      xr[p], a0);
                a1 = fmaf(fr1_w[i * 32 + P_ + p], xs[p], a1);
            }
            h1[i] = fmaxf(a0 + a1, 0.0f);
        }

        // fr2: 50 -> 25
        float h2[H2_];
#pragma unroll
        for (int i = 0; i < H2_; ++i) {
            float a0 = fr2_b[i], a1 = 0.0f;
#pragma unroll
            for (int k = 0; k < HID_; k += 2) {
                a0 = fmaf(fr2_w[i * HID_ + k],     h1[k],     a0);
                a1 = fmaf(fr2_w[i * HID_ + k + 1], h1[k + 1], a1);
            }
            h2[i] = fmaxf(a0 + a1, 0.0f);
        }

        // fr3: 25 -> 14, then aggregate into LDS (ds_add_f32)
#pragma unroll
        for (int d = 0; d < DE_; ++d) {
            float a0 = fr3_b[d], a1 = 0.0f;
#pragma unroll
            for (int k = 0; k < H2_ - 1; k += 2) {
                a0 = fmaf(fr3_w[d * H2_ + k],     h2[k],     a0);
                a1 = fmaf(fr3_w[d * H2_ + k + 1], h2[k + 1], a1);
            }
            a0 = fmaf(fr3_w[d * H2_ + (H2_ - 1)], h2[H2_ - 1], a0);
            float e = fmaxf(a0 + a1, 0.0f);
            atomicAdd(&s_eacc[q][d], e);
        }
    }
    __syncthreads();

    // object MLP layer 1: C = [x_col(16) | Ebar(14)] -> 50
    if (t < RPB * HID_) {
        int q = t / HID_, i = t % HID_;
        float a = fo1_b[i];
#pragma unroll
        for (int k = 0; k < P_; ++k)  a = fmaf(fo1_w[i * (P_ + DE_) + k],      s_x[q][k],    a);
#pragma unroll
        for (int k = 0; k < DE_; ++k) a = fmaf(fo1_w[i * (P_ + DE_) + P_ + k], s_eacc[q][k], a);
        s_h1[q][i] = fmaxf(a, 0.0f);
    }
    __syncthreads();
    if (t < RPB * H2_) {
        int q = t / H2_, i = t % H2_;
        float a = fo2_b[i];
#pragma unroll
        for (int k = 0; k < HID_; ++k) a = fmaf(fo2_w[i * HID_ + k], s_h1[q][k], a);
        s_h2[q][i] = fmaxf(a, 0.0f);
    }
    __syncthreads();
    if (t < RPB * DO_) {
        int q = t / DO_, i = t % DO_;
        float a = fo3_b[i];
#pragma unroll
        for (int k = 0; k < H2_; ++k) a = fmaf(fo3_w[i * H2_ + k], s_h2[q][k], a);
        O[b * (N_ * DO_) + (r0 + q) * DO_ + i] = fmaxf(a, 0.0f);
    }
}

// ---------------------------------------------------------------------------
// Kernel B: classifier fc1/fc2/fc3. One block (256 threads) per batch element.
// fc1 (1500->50): k-strided partials, coalesced weight reads, butterfly reduce.
// ---------------------------------------------------------------------------
__global__ __launch_bounds__(256) void classifier_kernel(
    const float* __restrict__ O,
    const float* __restrict__ fc1_w, const float* __restrict__ fc1_b,
    const float* __restrict__ fc2_w, const float* __restrict__ fc2_b,
    const float* __restrict__ fc3_w, const float* __restrict__ fc3_b,
    float* __restrict__ out)
{
    __shared__ float s_o[N_ * DO_];     // 1500
    __shared__ float s_part[4][HID_];
    __shared__ float s_h1[HID_];
    __shared__ float s_h2[H2_];

    const int b = blockIdx.x;
    const int t = threadIdx.x;
    const int lane = t & 63, w = t >> 6;

    for (int k = t; k < N_ * DO_; k += 256) s_o[k] = O[b * (N_ * DO_) + k];
    __syncthreads();

    float acc[HID_];
#pragma unroll
    for (int i = 0; i < HID_; ++i) acc[i] = 0.0f;

    for (int kb = 0; kb < N_ * DO_; kb += 256) {
        int k = kb + t;
        if (k < N_ * DO_) {
            float o = s_o[k];
#pragma unroll
            for (int i = 0; i < HID_; ++i)
                acc[i] = fmaf(fc1_w[i * (N_ * DO_) + k], o, acc[i]);  // lanes: consecutive k -> coalesced
        }
    }

#pragma unroll
    for (int i = 0; i < HID_; ++i) {
        float v = acc[i];
#pragma unroll
        for (int off = 32; off >= 1; off >>= 1) v += __shfl_xor(v, off);
        if (lane == i) s_part[w][i] = v;
    }
    __syncthreads();

    if (t < HID_) {
        float v = s_part[0][t] + s_part[1][t] + s_part[2][t] + s_part[3][t] + fc1_b[t];
        s_h1[t] = fmaxf(v, 0.0f);
    }
    __syncthreads();
    if (t < H2_) {
        float a = fc2_b[t];
#pragma unroll
        for (int k = 0; k < HID_; ++k) a = fmaf(fc2_w[t * HID_ + k], s_h1[k], a);
        s_h2[t] = fmaxf(a, 0.0f);
    }
    __syncthreads();
    if (t < NT_) {
        float a = fc3_b[t];
#pragma unroll
        for (int k = 0; k < H2_; ++k) a = fmaf(fc3_w[t * H2_ + k], s_h2[k], a);
        out[b * NT_ + t] = a;   // no relu on last layer
    }
}

extern "C" void kernel_launch(void* const* d_in, const int* in_sizes, int n_in,
                              void* d_out, int out_size, void* d_ws, size_t ws_size,
                              hipStream_t stream) {
    const float* x     = (const float*)d_in[0];
    // d_in[1] = recv (implied by edge ordering; unused)
    const int*   send  = (const int*)  d_in[2];
    const float* fr1_w = (const float*)d_in[3];
    const float* fr1_b = (const float*)d_in[4];
    const float* fr2_w = (const float*)d_in[5];
    const float* fr2_b = (const float*)d_in[6];
    const float* fr3_w = (const float*)d_in[7];
    const float* fr3_b = (const float*)d_in[8];
    const float* fo1_w = (const float*)d_in[9];
    const float* fo1_b = (const float*)d_in[10];
    const float* fo2_w = (const float*)d_in[11];
    const float* fo2_b = (const float*)d_in[12];
    const float* fo3_w = (const float*)d_in[13];
    const float* fo3_b = (const float*)d_in[14];
    const float* fc1_w = (const float*)d_in[15];
    const float* fc1_b = (const float*)d_in[16];
    const float* fc2_w = (const float*)d_in[17];
    const float* fc2_b = (const float*)d_in[18];
    const float* fc3_w = (const float*)d_in[19];
    const float* fc3_b = (const float*)d_in[20];

    float* O = (float*)d_ws;            // B * N * DO = 384000 floats = 1.5 MB
    float* out = (float*)d_out;

    edge_obj_kernel<<<B_ * (N_ / RPB), TPB_A, 0, stream>>>(
        x, send, fr1_w, fr1_b, fr2_w, fr2_b, fr3_w, fr3_b,
        fo1_w, fo1_b, fo2_w, fo2_b, fo3_w, fo3_b, O);

    classifier_kernel<<<B_, 256, 0, stream>>>(
        O, fc1_w, fc1_b, fc2_w, fc2_b, fc3_w, fc3_b, out);
}

// Round 2
// 191.224 us; speedup vs baseline: 5.6239x; 5.6239x over previous
//
#include <hip/hip_runtime.h>

#define N_   150
#define P_   16
#define DE_  14
#define DO_  10
#define NT_  5
#define B_   256
#define NRE  22350          // N*(N-1)
#define H2_  25
#define HID_ 50

typedef float    f32x4 __attribute__((ext_vector_type(4)));
typedef _Float16 f16x8 __attribute__((ext_vector_type(8)));
typedef _Float16 f16x2 __attribute__((ext_vector_type(2)));

// may_alias views for LDS mixed-type access (avoid TBAA reordering)
typedef f16x8 f16x8_a __attribute__((may_alias));
typedef int2  int2_a  __attribute__((may_alias));

// ---- ws layout (bytes) ----
#define EBAR_OFF 0u          // f32 [256][150][14]  = 2150400 B
#define O_OFF    2150400u    // f32 [256][1500]     = 1536000 B
#define XT_OFF   3686400u    // f16 [256][150][16]  = 1228800 B
#define W1E_OFF  4915200u    // f16 [64][32]
#define W1O_OFF  4919296u    // f16 [64][32]
#define W2E_OFF  4923392u    // f16 [32][64]
#define W2O_OFF  4927488u    // f16 [32][64]
#define W3E_OFF  4931584u    // f16 [16][32]
#define W3O_OFF  4932608u    // f16 [16][32]
#define B1E_OFF  4933632u    // f32 [64]
#define B1O_OFF  4933888u
#define B2E_OFF  4934144u    // f32 [32]
#define B2O_OFF  4934272u
#define B3E_OFF  4934400u    // f32 [16]
#define B3O_OFF  4934464u

// ---------------------------------------------------------------------------
// prep: xT (fp16 transpose of x), padded fp16 weights, padded f32 biases
// ---------------------------------------------------------------------------
__global__ __launch_bounds__(256) void prep_kernel(
    const float* __restrict__ x,
    const float* __restrict__ fr1_w, const float* __restrict__ fr1_b,
    const float* __restrict__ fr2_w, const float* __restrict__ fr2_b,
    const float* __restrict__ fr3_w, const float* __restrict__ fr3_b,
    const float* __restrict__ fo1_w, const float* __restrict__ fo1_b,
    const float* __restrict__ fo2_w, const float* __restrict__ fo2_b,
    const float* __restrict__ fo3_w, const float* __restrict__ fo3_b,
    char* __restrict__ ws)
{
    int tid = blockIdx.x * 256 + threadIdx.x;
    if (tid < 614400) {                       // xT[b][n][p] = x[b][p][n]
        int b = tid / (N_ * P_); int r = tid - b * (N_ * P_);
        int n = r >> 4, p = r & 15;
        ((_Float16*)(ws + XT_OFF))[tid] = (_Float16)x[b * (P_ * N_) + p * N_ + n];
        return;
    }
    int t = tid - 614400;
    if (t < 2048) { int n = t >> 5, k = t & 31;          // W1e [64][32]
        ((_Float16*)(ws + W1E_OFF))[t] = (_Float16)((n < 50) ? fr1_w[n * 32 + k] : 0.f); return; }
    t -= 2048;
    if (t < 2048) { int n = t >> 5, k = t & 31;          // W1o [64][32]
        ((_Float16*)(ws + W1O_OFF))[t] = (_Float16)((n < 50 && k < 30) ? fo1_w[n * 30 + k] : 0.f); return; }
    t -= 2048;
    if (t < 2048) { int n = t >> 6, k = t & 63;          // W2e [32][64]
        ((_Float16*)(ws + W2E_OFF))[t] = (_Float16)((n < 25 && k < 50) ? fr2_w[n * 50 + k] : 0.f); return; }
    t -= 2048;
    if (t < 2048) { int n = t >> 6, k = t & 63;          // W2o [32][64]
        ((_Float16*)(ws + W2O_OFF))[t] = (_Float16)((n < 25 && k < 50) ? fo2_w[n * 50 + k] : 0.f); return; }
    t -= 2048;
    if (t < 512) { int n = t >> 5, k = t & 31;           // W3e [16][32]
        ((_Float16*)(ws + W3E_OFF))[t] = (_Float16)((n < 14 && k < 25) ? fr3_w[n * 25 + k] : 0.f); return; }
    t -= 512;
    if (t < 512) { int n = t >> 5, k = t & 31;           // W3o [16][32]
        ((_Float16*)(ws + W3O_OFF))[t] = (_Float16)((n < 10 && k < 25) ? fo3_w[n * 25 + k] : 0.f); return; }
    t -= 512;
    if (t < 64) { ((float*)(ws + B1E_OFF))[t] = (t < 50) ? fr1_b[t] : 0.f; return; }
    t -= 64;
    if (t < 64) { ((float*)(ws + B1O_OFF))[t] = (t < 50) ? fo1_b[t] : 0.f; return; }
    t -= 64;
    if (t < 32) { ((float*)(ws + B2E_OFF))[t] = (t < 25) ? fr2_b[t] : 0.f; return; }
    t -= 32;
    if (t < 32) { ((float*)(ws + B2O_OFF))[t] = (t < 25) ? fo2_b[t] : 0.f; return; }
    t -= 32;
    if (t < 16) { ((float*)(ws + B3E_OFF))[t] = (t < 14) ? fr3_b[t] : 0.f; return; }
    t -= 16;
    if (t < 16) { ((float*)(ws + B3O_OFF))[t] = (t < 10) ? fo3_b[t] : 0.f; return; }
}

// 16-lane-row sum via DPP row_ror (VALU pipe, no LDS traffic)
template<int CTRL>
__device__ __forceinline__ float dppadd(float v) {
    int s = __builtin_amdgcn_update_dpp(0, __builtin_bit_cast(int, v), CTRL, 0xF, 0xF, true);
    return v + __builtin_bit_cast(float, s);
}
__device__ __forceinline__ float dpp_sum16(float v) {
    v = dppadd<0x121>(v);   // row_ror:1
    v = dppadd<0x122>(v);   // row_ror:2
    v = dppadd<0x124>(v);   // row_ror:4
    v = dppadd<0x128>(v);   // row_ror:8
    return v;
}

// ---------------------------------------------------------------------------
// 3-layer MLP via mfma_f32_16x16x32_f16. A = weights (rows=n), B = 16 batch
// rows (cols). Per-wave private LDS chaining, XOR-swizzled -> no barriers.
// OBJ=false: edge MLP + receiver aggregation (atomicAdd into Ebar).
// OBJ=true : object MLP, writes O.
// ---------------------------------------------------------------------------
template<int TPW, bool OBJ>
__global__ __launch_bounds__(256) void mlp3_kernel(char* __restrict__ ws)
{
    const _Float16* __restrict__ xT = (const _Float16*)(ws + XT_OFF);
    const _Float16* __restrict__ W1 = (const _Float16*)(ws + (OBJ ? W1O_OFF : W1E_OFF));
    const _Float16* __restrict__ W2 = (const _Float16*)(ws + (OBJ ? W2O_OFF : W2E_OFF));
    const _Float16* __restrict__ W3 = (const _Float16*)(ws + (OBJ ? W3O_OFF : W3E_OFF));
    const float* __restrict__ b1 = (const float*)(ws + (OBJ ? B1O_OFF : B1E_OFF));
    const float* __restrict__ b2 = (const float*)(ws + (OBJ ? B2O_OFF : B2E_OFF));
    const float* __restrict__ b3 = (const float*)(ws + (OBJ ? B3O_OFF : B3E_OFF));
    float* __restrict__ Ebar = (float*)(ws + EBAR_OFF);
    float* __restrict__ O    = (float*)(ws + O_OFF);

    const int t = threadIdx.x;
    const int lane = t & 63, wid = t >> 6;
    const int e16 = lane & 15, g = lane >> 4;

    __shared__ __align__(16) _Float16 s_h1[4][16 * 64];   // per-wave [col e][n] fp16
    __shared__ __align__(16) _Float16 s_h2[4][16 * 32];
    char* h1b = (char*)&s_h1[wid][0];
    char* h2b = (char*)&s_h2[wid][0];

    // weight A-frags: lane holds row n=(l&15), k=(l>>4)*8+j
    f16x8 A1[4], A2[2][2], A3;
#pragma unroll
    for (int nt = 0; nt < 4; ++nt)
        A1[nt] = *(const f16x8*)&W1[(nt * 16 + e16) * 32 + g * 8];
#pragma unroll
    for (int nt = 0; nt < 2; ++nt)
#pragma unroll
        for (int kt = 0; kt < 2; ++kt)
            A2[nt][kt] = *(const f16x8*)&W2[(nt * 16 + e16) * 64 + kt * 32 + g * 8];
    A3 = *(const f16x8*)&W3[e16 * 32 + g * 8];

    // bias C-frags: lane's rows n = nt*16 + g*4 + v
    f32x4 C1[4], C2[2], C3;
#pragma unroll
    for (int nt = 0; nt < 4; ++nt) C1[nt] = *(const f32x4*)&b1[nt * 16 + g * 4];
#pragma unroll
    for (int nt = 0; nt < 2; ++nt) C2[nt] = *(const f32x4*)&b2[nt * 16 + g * 4];
    C3 = *(const f32x4*)&b3[g * 4];

    int b = 0, tile0;
    if (OBJ) {
        tile0 = blockIdx.x * (4 * TPW) + wid * TPW;
    } else {
        b = blockIdx.x / 88;
        tile0 = (blockIdx.x % 88) * (4 * TPW) + wid * TPW;
    }

    const int sw1 = (e16 & 7) << 4;
    const int sw2 = (e16 & 3) << 4;

    for (int tt = 0; tt < TPW; ++tt) {
        const int tile = tile0 + tt;
        if (!OBJ && tile * 16 >= NRE) break;

        // ---- build B-frag: lane holds col (l&15), k=(l>>4)*8+j ----
        f16x8 Bf;
        int r_e = 0, ecol;
        if (!OBJ) {
            int e = tile * 16 + e16;
            ecol = e;
            int ec = e < NRE ? e : NRE - 1;
            unsigned r = (unsigned)ec / 149u;
            unsigned sp = (unsigned)ec - r * 149u;
            int s = sp + (sp >= r ? 1 : 0);
            r_e = (int)r;
            int node = (g < 2) ? (int)r : s;
            Bf = *(const f16x8*)&xT[(b * N_ + node) * 16 + (g & 1) * 8];
        } else {
            int m = tile * 16 + e16;     // m = b*150 + n, < 38400 always
            ecol = m;
            if (g < 2) {
                Bf = *(const f16x8*)&xT[m * 16 + g * 8];
            } else {
                const float* ep = &Ebar[m * DE_];
                int kb = (g & 1) * 8;
#pragma unroll
                for (int j = 0; j < 8; ++j) {
                    int k = kb + j;
                    float v = (k < DE_) ? ep[k] : 0.f;
                    Bf[j] = (_Float16)v;
                }
            }
        }

        // ---- layer 1: 4 MFMAs, relu, fp16 -> swizzled LDS ----
#pragma unroll
        for (int nt = 0; nt < 4; ++nt) {
            f32x4 acc = __builtin_amdgcn_mfma_f32_16x16x32_f16(A1[nt], Bf, C1[nt], 0, 0, 0);
            f16x2 lo = { (_Float16)fmaxf(acc[0], 0.f), (_Float16)fmaxf(acc[1], 0.f) };
            f16x2 hi = { (_Float16)fmaxf(acc[2], 0.f), (_Float16)fmaxf(acc[3], 0.f) };
            int2 pk; pk.x = __builtin_bit_cast(int, lo); pk.y = __builtin_bit_cast(int, hi);
            int byte = (e16 * 128 + nt * 32 + g * 8) ^ sw1;
            *(int2_a*)(h1b + byte) = pk;
        }

        // ---- layer 2: read h1, 4 MFMAs, relu -> h2 ----
        f16x8 Bf2[2];
#pragma unroll
        for (int kt = 0; kt < 2; ++kt)
            Bf2[kt] = *(const f16x8_a*)(h1b + ((e16 * 128 + kt * 64 + g * 16) ^ sw1));
        f32x4 acc2[2];
#pragma unroll
        for (int nt = 0; nt < 2; ++nt) {
            acc2[nt] = __builtin_amdgcn_mfma_f32_16x16x32_f16(A2[nt][0], Bf2[0], C2[nt], 0, 0, 0);
            acc2[nt] = __builtin_amdgcn_mfma_f32_16x16x32_f16(A2[nt][1], Bf2[1], acc2[nt], 0, 0, 0);
            f16x2 lo = { (_Float16)fmaxf(acc2[nt][0], 0.f), (_Float16)fmaxf(acc2[nt][1], 0.f) };
            f16x2 hi = { (_Float16)fmaxf(acc2[nt][2], 0.f), (_Float16)fmaxf(acc2[nt][3], 0.f) };
            int2 pk; pk.x = __builtin_bit_cast(int, lo); pk.y = __builtin_bit_cast(int, hi);
            int byte = (e16 * 64 + nt * 32 + g * 8) ^ sw2;
            *(int2_a*)(h2b + byte) = pk;
        }

        // ---- layer 3: 1 MFMA ----
        f16x8 Bf3 = *(const f16x8_a*)(h2b + ((e16 * 64 + g * 16) ^ sw2));
        f32x4 acc3 = __builtin_amdgcn_mfma_f32_16x16x32_f16(A3, Bf3, C3, 0, 0, 0);

        if (OBJ) {
            int m = ecol;
#pragma unroll
            for (int v = 0; v < 4; ++v) {
                int d = g * 4 + v;
                if (d < DO_) O[m * DO_ + d] = fmaxf(acc3[v], 0.f);
            }
        } else {
            // receiver aggregation: tile spans <=2 consecutive receivers
            bool valid = (ecol < NRE);
            int r0 = (tile * 16) / 149;                 // uniform
            bool two = ((tile * 16 + 15) / 149 != r0);  // uniform
            bool mA = valid && (r_e == r0);
#pragma unroll
            for (int v = 0; v < 4; ++v) {
                float xv = mA ? fmaxf(acc3[v], 0.f) : 0.f;
                xv = dpp_sum16(xv);
                int d = g * 4 + v;
                if (e16 == 0 && d < DE_)
                    atomicAdd(&Ebar[(b * N_ + r0) * DE_ + d], xv);
            }
            if (two) {
                bool mB = valid && (r_e == r0 + 1);
#pragma unroll
                for (int v = 0; v < 4; ++v) {
                    float xv = mB ? fmaxf(acc3[v], 0.f) : 0.f;
                    xv = dpp_sum16(xv);
                    int d = g * 4 + v;
                    if (e16 == 0 && d < DE_)
                        atomicAdd(&Ebar[(b * N_ + (r0 + 1)) * DE_ + d], xv);
                }
            }
        }
    }
}

// ---------------------------------------------------------------------------
// classifier fc1/fc2/fc3 (fp32), one block per batch element
// ---------------------------------------------------------------------------
__global__ __launch_bounds__(256) void classifier_kernel(
    const float* __restrict__ O,
    const float* __restrict__ fc1_w, const float* __restrict__ fc1_b,
    const float* __restrict__ fc2_w, const float* __restrict__ fc2_b,
    const float* __restrict__ fc3_w, const float* __restrict__ fc3_b,
    float* __restrict__ out)
{
    __shared__ float s_o[N_ * DO_];
    __shared__ float s_part[4][HID_];
    __shared__ float s_h1[HID_];
    __shared__ float s_h2[H2_];

    const int b = blockIdx.x;
    const int t = threadIdx.x;
    const int lane = t & 63, w = t >> 6;

    for (int k = t; k < N_ * DO_; k += 256) s_o[k] = O[b * (N_ * DO_) + k];
    __syncthreads();

    float acc[HID_];
#pragma unroll
    for (int i = 0; i < HID_; ++i) acc[i] = 0.0f;

    for (int kb = 0; kb < N_ * DO_; kb += 256) {
        int k = kb + t;
        if (k < N_ * DO_) {
            float o = s_o[k];
#pragma unroll
            for (int i = 0; i < HID_; ++i)
                acc[i] = fmaf(fc1_w[i * (N_ * DO_) + k], o, acc[i]);
        }
    }

#pragma unroll
    for (int i = 0; i < HID_; ++i) {
        float v = acc[i];
#pragma unroll
        for (int off = 32; off >= 1; off >>= 1) v += __shfl_xor(v, off);
        if (lane == i) s_part[w][i] = v;
    }
    __syncthreads();

    if (t < HID_) {
        float v = s_part[0][t] + s_part[1][t] + s_part[2][t] + s_part[3][t] + fc1_b[t];
        s_h1[t] = fmaxf(v, 0.0f);
    }
    __syncthreads();
    if (t < H2_) {
        float a = fc2_b[t];
#pragma unroll
        for (int k = 0; k < HID_; ++k) a = fmaf(fc2_w[t * HID_ + k], s_h1[k], a);
        s_h2[t] = fmaxf(a, 0.0f);
    }
    __syncthreads();
    if (t < NT_) {
        float a = fc3_b[t];
#pragma unroll
        for (int k = 0; k < H2_; ++k) a = fmaf(fc3_w[t * H2_ + k], s_h2[k], a);
        out[b * NT_ + t] = a;
    }
}

extern "C" void kernel_launch(void* const* d_in, const int* in_sizes, int n_in,
                              void* d_out, int out_size, void* d_ws, size_t ws_size,
                              hipStream_t stream) {
    const float* x     = (const float*)d_in[0];
    const float* fr1_w = (const float*)d_in[3];
    const float* fr1_b = (const float*)d_in[4];
    const float* fr2_w = (const float*)d_in[5];
    const float* fr2_b = (const float*)d_in[6];
    const float* fr3_w = (const float*)d_in[7];
    const float* fr3_b = (const float*)d_in[8];
    const float* fo1_w = (const float*)d_in[9];
    const float* fo1_b = (const float*)d_in[10];
    const float* fo2_w = (const float*)d_in[11];
    const float* fo2_b = (const float*)d_in[12];
    const float* fo3_w = (const float*)d_in[13];
    const float* fo3_b = (const float*)d_in[14];
    const float* fc1_w = (const float*)d_in[15];
    const float* fc1_b = (const float*)d_in[16];
    const float* fc2_w = (const float*)d_in[17];
    const float* fc2_b = (const float*)d_in[18];
    const float* fc3_w = (const float*)d_in[19];
    const float* fc3_b = (const float*)d_in[20];

    char* ws = (char*)d_ws;
    float* out = (float*)d_out;

    hipMemsetAsync(ws + EBAR_OFF, 0, 2150400, stream);          // zero Ebar
    prep_kernel<<<2437, 256, 0, stream>>>(x, fr1_w, fr1_b, fr2_w, fr2_b, fr3_w, fr3_b,
                                          fo1_w, fo1_b, fo2_w, fo2_b, fo3_w, fo3_b, ws);
    mlp3_kernel<4, false><<<B_ * 88, 256, 0, stream>>>(ws);     // edge MLP + aggregate
    mlp3_kernel<1, true ><<<600, 256, 0, stream>>>(ws);         // object MLP
    classifier_kernel<<<B_, 256, 0, stream>>>((const float*)(ws + O_OFF),
                                              fc1_w, fc1_b, fc2_w, fc2_b, fc3_w, fc3_b, out);
}

// Round 4
// 139.024 us; speedup vs baseline: 7.7355x; 1.3755x over previous
//
#include <hip/hip_runtime.h>

#define N_   150
#define P_   16
#define DE_  14
#define DO_  10
#define NT_  5
#define B_   256
#define NRE  22350          // N*(N-1)
#define H2_  25
#define HID_ 50

typedef float    f32x4 __attribute__((ext_vector_type(4)));
typedef _Float16 f16x8 __attribute__((ext_vector_type(8)));

typedef f16x8 f16x8_a __attribute__((may_alias));
typedef int2  int2_a  __attribute__((may_alias));
typedef f32x4 f32x4_a __attribute__((may_alias));

// ---- ws layout (bytes) ----
#define EBAR_OFF 0u          // f32 [38400][16] (rows padded 14->16) = 2457600
#define O_OFF    2457600u    // f16 [38400][10]                      =  768000
#define XT_OFF   3225600u    // f16 [38400][16]                      = 1228800
#define W1E_OFF  4454400u    // f16 [64][32]
#define W1O_OFF  4458496u    // f16 [64][32]
#define W2E_OFF  4462592u    // f16 [32][64]
#define W2O_OFF  4466688u    // f16 [32][64]
#define W3E_OFF  4470784u    // f16 [16][32]
#define W3O_OFF  4471808u    // f16 [16][32]
#define B1E_OFF  4472832u    // f32 [64]
#define B1O_OFF  4473088u
#define B2E_OFF  4473344u    // f32 [32]
#define B2O_OFF  4473472u
#define B3E_OFF  4473600u    // f32 [16]
#define B3O_OFF  4473664u
// total 4473728 B

// ---------------------------------------------------------------------------
// prep: xT (fp16 transpose of x), Ebar zero, padded fp16 weights, f32 biases
// ---------------------------------------------------------------------------
__global__ __launch_bounds__(256) void prep_kernel(
    const float* __restrict__ x,
    const float* __restrict__ fr1_w, const float* __restrict__ fr1_b,
    const float* __restrict__ fr2_w, const float* __restrict__ fr2_b,
    const float* __restrict__ fr3_w, const float* __restrict__ fr3_b,
    const float* __restrict__ fo1_w, const float* __restrict__ fo1_b,
    const float* __restrict__ fo2_w, const float* __restrict__ fo2_b,
    const float* __restrict__ fo3_w, const float* __restrict__ fo3_b,
    char* __restrict__ ws)
{
    int tid = blockIdx.x * 256 + threadIdx.x;
    if (tid < 614400) {                       // xT[b][n][p] = x[b][p][n]
        int b = tid / 2400; int rr = tid - b * 2400;
        int n = rr >> 4, p = rr & 15;
        ((_Float16*)(ws + XT_OFF))[tid] = (_Float16)x[b * 2400 + p * N_ + n];
        return;
    }
    int t = tid - 614400;
    if (t < 614400) { ((float*)(ws + EBAR_OFF))[t] = 0.f; return; }  // Ebar = 0
    t -= 614400;
    if (t < 2048) { int n = t >> 5, k = t & 31;          // W1e [64][32]
        ((_Float16*)(ws + W1E_OFF))[t] = (_Float16)((n < 50) ? fr1_w[n * 32 + k] : 0.f); return; }
    t -= 2048;
    if (t < 2048) { int n = t >> 5, k = t & 31;          // W1o [64][32]
        ((_Float16*)(ws + W1O_OFF))[t] = (_Float16)((n < 50 && k < 30) ? fo1_w[n * 30 + k] : 0.f); return; }
    t -= 2048;
    if (t < 2048) { int n = t >> 6, k = t & 63;          // W2e [32][64]
        ((_Float16*)(ws + W2E_OFF))[t] = (_Float16)((n < 25 && k < 50) ? fr2_w[n * 50 + k] : 0.f); return; }
    t -= 2048;
    if (t < 2048) { int n = t >> 6, k = t & 63;          // W2o [32][64]
        ((_Float16*)(ws + W2O_OFF))[t] = (_Float16)((n < 25 && k < 50) ? fo2_w[n * 50 + k] : 0.f); return; }
    t -= 2048;
    if (t < 512) { int n = t >> 5, k = t & 31;           // W3e [16][32]
        ((_Float16*)(ws + W3E_OFF))[t] = (_Float16)((n < 14 && k < 25) ? fr3_w[n * 25 + k] : 0.f); return; }
    t -= 512;
    if (t < 512) { int n = t >> 5, k = t & 31;           // W3o [16][32]
        ((_Float16*)(ws + W3O_OFF))[t] = (_Float16)((n < 10 && k < 25) ? fo3_w[n * 25 + k] : 0.f); return; }
    t -= 512;
    if (t < 64) { ((float*)(ws + B1E_OFF))[t] = (t < 50) ? fr1_b[t] : 0.f; return; }
    t -= 64;
    if (t < 64) { ((float*)(ws + B1O_OFF))[t] = (t < 50) ? fo1_b[t] : 0.f; return; }
    t -= 64;
    if (t < 32) { ((float*)(ws + B2E_OFF))[t] = (t < 25) ? fr2_b[t] : 0.f; return; }
    t -= 32;
    if (t < 32) { ((float*)(ws + B2O_OFF))[t] = (t < 25) ? fo2_b[t] : 0.f; return; }
    t -= 32;
    if (t < 16) { ((float*)(ws + B3E_OFF))[t] = (t < 14) ? fr3_b[t] : 0.f; return; }
    t -= 16;
    if (t < 16) { ((float*)(ws + B3O_OFF))[t] = (t < 10) ? fo3_b[t] : 0.f; return; }
}

__device__ __forceinline__ unsigned pk2(float a, float b) {
    auto p = __builtin_amdgcn_cvt_pkrtz(a, b);   // __fp16 ext_vector(2)
    return __builtin_bit_cast(unsigned, p);
}
__device__ __forceinline__ unsigned pkrelu(float a, float b) {
    return pk2(fmaxf(a, 0.f), fmaxf(b, 0.f));
}

// reduce over g (lanes +-16, +-32), then one predicated atomic (14 lanes)
__device__ __forceinline__ void flush_ebar(float* __restrict__ Ebar, int row,
                                           float acc, int lane) {
    acc += __shfl_xor(acc, 16);
    acc += __shfl_xor(acc, 32);
    if (lane < DE_) atomicAdd(&Ebar[row * 16 + lane], acc);
}

// ---------------------------------------------------------------------------
// 3-layer MLP via mfma_f32_16x16x32_f16. Layers 1-2: A=W (rows=n), B=16 cols.
// Layer 3 operand-swapped: D[row=col-idx][col=d] so aggregation/stores are
// lane-parallel in d. LDS layout [granule16B][e16][16B] -> conflict-free.
// ---------------------------------------------------------------------------
template<int TPW, bool OBJ>
__global__ __launch_bounds__(256) void mlp3_kernel(char* __restrict__ ws)
{
    const _Float16* __restrict__ xT = (const _Float16*)(ws + XT_OFF);
    const _Float16* __restrict__ W1 = (const _Float16*)(ws + (OBJ ? W1O_OFF : W1E_OFF));
    const _Float16* __restrict__ W2 = (const _Float16*)(ws + (OBJ ? W2O_OFF : W2E_OFF));
    const _Float16* __restrict__ W3 = (const _Float16*)(ws + (OBJ ? W3O_OFF : W3E_OFF));
    const float* __restrict__ b1 = (const float*)(ws + (OBJ ? B1O_OFF : B1E_OFF));
    const float* __restrict__ b2 = (const float*)(ws + (OBJ ? B2O_OFF : B2E_OFF));
    const float* __restrict__ b3 = (const float*)(ws + (OBJ ? B3O_OFF : B3E_OFF));
    float*     __restrict__ Ebar = (float*)(ws + EBAR_OFF);
    _Float16*  __restrict__ O    = (_Float16*)(ws + O_OFF);

    const int t = threadIdx.x;
    const int lane = t & 63, wid = t >> 6;
    const int e16 = lane & 15, g = lane >> 4;

    // per-wave private LDS: h1 = 8 granules * 256B, h2 = 4 granules * 256B
    __shared__ __align__(16) char s_lds[4][3072];
    char* ldsw = s_lds[wid];
    const int wsub = (g >> 1) * 256 + e16 * 16 + (g & 1) * 8;
    char*       h1w = ldsw + wsub;                 // + nt*512 (imm)
    char*       h2w = ldsw + 2048 + wsub;          // + nt*512 (imm)
    const int rsub = g * 256 + e16 * 16;
    const char* h1r = ldsw + rsub;                 // + kt*1024 (imm)
    const char* h2r = ldsw + 2048 + rsub;

    // weight A-frags: lane = row n=(l&15), k=(l>>4)*8+j
    f16x8 A1[4], A2[2][2], A3;
#pragma unroll
    for (int nt = 0; nt < 4; ++nt)
        A1[nt] = *(const f16x8*)&W1[(nt * 16 + e16) * 32 + g * 8];
#pragma unroll
    for (int nt = 0; nt < 2; ++nt)
#pragma unroll
        for (int kt = 0; kt < 2; ++kt)
            A2[nt][kt] = *(const f16x8*)&W2[(nt * 16 + e16) * 64 + kt * 32 + g * 8];
    A3 = *(const f16x8*)&W3[e16 * 32 + g * 8];

    // bias C-frags
    f32x4 C1[4], C2[2];
#pragma unroll
    for (int nt = 0; nt < 4; ++nt) C1[nt] = *(const f32x4*)&b1[nt * 16 + g * 4];
#pragma unroll
    for (int nt = 0; nt < 2; ++nt) C2[nt] = *(const f32x4*)&b2[nt * 16 + g * 4];
    const float b3v = b3[e16];               // swapped L3: bias per col d=e16
    const f32x4 C3 = { b3v, b3v, b3v, b3v };

    int b = 0, tile0;
    if constexpr (OBJ) {
        tile0 = blockIdx.x * 4 + wid;        // 600 blocks * 4 waves = 2400 tiles
    } else {
        b = blockIdx.x / 44;
        tile0 = (blockIdx.x % 44) * 32 + wid * TPW;
    }
    const _Float16* __restrict__ xTb = xT + b * 2400;

    int   cur_r = -1;
    float acc_r = 0.f;

    for (int tt = 0; tt < TPW; ++tt) {
        const int tile = tile0 + tt;
        if constexpr (!OBJ) { if (tile * 16 >= NRE) break; }

        // ---- B-frag: lane holds col (l&15), k=(l>>4)*8+j ----
        f16x8 Bf;
        if constexpr (!OBJ) {
            int e = tile * 16 + e16;
            int ec = e < NRE ? e : NRE - 1;
            unsigned r = (unsigned)ec / 149u;
            unsigned sp = (unsigned)ec - r * 149u;
            int s = (int)sp + (sp >= r ? 1 : 0);
            int node = (g < 2) ? (int)r : s;
            Bf = *(const f16x8*)&xTb[node * 16 + (g & 1) * 8];
        } else {
            int m = tile * 16 + e16;
            if (g < 2) {
                Bf = *(const f16x8*)&xT[m * 16 + g * 8];
            } else {
                const float* ep = &Ebar[m * 16 + (g & 1) * 8];
                f32x4 u0 = *(const f32x4_a*)ep;
                f32x4 u1 = *(const f32x4_a*)(ep + 4);
                uint4 uw;
                uw.x = pk2(u0[0], u0[1]); uw.y = pk2(u0[2], u0[3]);
                uw.z = pk2(u1[0], u1[1]); uw.w = pk2(u1[2], u1[3]);
                Bf = __builtin_bit_cast(f16x8, uw);
            }
        }

        // ---- layer 1: 4 MFMAs -> relu/pack -> LDS ----
#pragma unroll
        for (int nt = 0; nt < 4; ++nt) {
            f32x4 a = __builtin_amdgcn_mfma_f32_16x16x32_f16(A1[nt], Bf, C1[nt], 0, 0, 0);
            int2 pkw; pkw.x = (int)pkrelu(a[0], a[1]); pkw.y = (int)pkrelu(a[2], a[3]);
            *(int2_a*)(h1w + nt * 512) = pkw;
        }

        // ---- layer 2: 2 b128 reads, 4 MFMAs -> h2 ----
        f16x8 Bf2a = *(const f16x8_a*)(h1r);
        f16x8 Bf2b = *(const f16x8_a*)(h1r + 1024);
#pragma unroll
        for (int nt = 0; nt < 2; ++nt) {
            f32x4 a = __builtin_amdgcn_mfma_f32_16x16x32_f16(A2[nt][0], Bf2a, C2[nt], 0, 0, 0);
            a = __builtin_amdgcn_mfma_f32_16x16x32_f16(A2[nt][1], Bf2b, a, 0, 0, 0);
            int2 pkw; pkw.x = (int)pkrelu(a[0], a[1]); pkw.y = (int)pkrelu(a[2], a[3]);
            *(int2_a*)(h2w + nt * 512) = pkw;
        }

        // ---- layer 3 (operand-swapped): D[row=col-idx][col=d] ----
        f16x8 Af3 = *(const f16x8_a*)(h2r);
        f32x4 acc3 = __builtin_amdgcn_mfma_f32_16x16x32_f16(Af3, A3, C3, 0, 0, 0);

        if constexpr (OBJ) {
            if (e16 < DO_) {
#pragma unroll
                for (int v = 0; v < 4; ++v)
                    O[(tile * 16 + g * 4 + v) * DO_ + e16] = (_Float16)fmaxf(acc3[v], 0.f);
            }
        } else {
            const int r0 = (tile * 16) / 149;             // wave-uniform
            const int rsplit = (r0 + 1) * 149;
            const bool two = (tile * 16 + 15) >= rsplit;  // wave-uniform

            if (r0 != cur_r) {                            // aligned boundary
                if (cur_r >= 0) flush_ebar(Ebar, b * N_ + cur_r, acc_r, lane);
                acc_r = 0.f; cur_r = r0;
            }
            if (!two) {
                acc_r += fmaxf(acc3[0], 0.f) + fmaxf(acc3[1], 0.f)
                       + fmaxf(acc3[2], 0.f) + fmaxf(acc3[3], 0.f);
            } else {
                float sA = 0.f, sB = 0.f;
                const int ebase = tile * 16 + g * 4;
#pragma unroll
                for (int v = 0; v < 4; ++v) {
                    float val = fmaxf(acc3[v], 0.f);
                    if (ebase + v >= rsplit) sB += val; else sA += val;
                }
                acc_r += sA;
                flush_ebar(Ebar, b * N_ + r0, acc_r, lane);  // r0 complete here
                acc_r = sB; cur_r = r0 + 1;                  // may be N_ on last tile
            }
        }
    }
    if constexpr (!OBJ) {
        if (cur_r >= 0 && cur_r < N_) flush_ebar(Ebar, b * N_ + cur_r, acc_r, lane);
    }
}

// ---------------------------------------------------------------------------
// classifier fc1/fc2/fc3 (fp32), one block per batch element; O read as fp16
// ---------------------------------------------------------------------------
__global__ __launch_bounds__(256) void classifier_kernel(
    const _Float16* __restrict__ O,
    const float* __restrict__ fc1_w, const float* __restrict__ fc1_b,
    const float* __restrict__ fc2_w, const float* __restrict__ fc2_b,
    const float* __restrict__ fc3_w, const float* __restrict__ fc3_b,
    float* __restrict__ out)
{
    __shared__ float s_o[N_ * DO_];
    __shared__ float s_part[4][HID_];
    __shared__ float s_h1[HID_];
    __shared__ float s_h2[H2_];

    const int b = blockIdx.x;
    const int t = threadIdx.x;
    const int lane = t & 63, w = t >> 6;

    const _Float16* Ob = O + b * (N_ * DO_);
    for (int k = t; k < N_ * DO_; k += 256) s_o[k] = (float)Ob[k];
    __syncthreads();

    float acc[HID_];
#pragma unroll
    for (int i = 0; i < HID_; ++i) acc[i] = 0.0f;

    for (int kb = 0; kb < N_ * DO_; kb += 256) {
        int k = kb + t;
        if (k < N_ * DO_) {
            float o = s_o[k];
#pragma unroll
            for (int i = 0; i < HID_; ++i)
                acc[i] = fmaf(fc1_w[i * (N_ * DO_) + k], o, acc[i]);
        }
    }

#pragma unroll
    for (int i = 0; i < HID_; ++i) {
        float v = acc[i];
#pragma unroll
        for (int off = 32; off >= 1; off >>= 1) v += __shfl_xor(v, off);
        if (lane == i) s_part[w][i] = v;
    }
    __syncthreads();

    if (t < HID_) {
        float v = s_part[0][t] + s_part[1][t] + s_part[2][t] + s_part[3][t] + fc1_b[t];
        s_h1[t] = fmaxf(v, 0.0f);
    }
    __syncthreads();
    if (t < H2_) {
        float a = fc2_b[t];
#pragma unroll
        for (int k = 0; k < HID_; ++k) a = fmaf(fc2_w[t * HID_ + k], s_h1[k], a);
        s_h2[t] = fmaxf(a, 0.0f);
    }
    __syncthreads();
    if (t < NT_) {
        float a = fc3_b[t];
#pragma unroll
        for (int k = 0; k < H2_; ++k) a = fmaf(fc3_w[t * H2_ + k], s_h2[k], a);
        out[b * NT_ + t] = a;
    }
}

extern "C" void kernel_launch(void* const* d_in, const int* in_sizes, int n_in,
                              void* d_out, int out_size, void* d_ws, size_t ws_size,
                              hipStream_t stream) {
    const float* x     = (const float*)d_in[0];
    const float* fr1_w = (const float*)d_in[3];
    const float* fr1_b = (const float*)d_in[4];
    const float* fr2_w = (const float*)d_in[5];
    const float* fr2_b = (const float*)d_in[6];
    const float* fr3_w = (const float*)d_in[7];
    const float* fr3_b = (const float*)d_in[8];
    const float* fo1_w = (const float*)d_in[9];
    const float* fo1_b = (const float*)d_in[10];
    const float* fo2_w = (const float*)d_in[11];
    const float* fo2_b = (const float*)d_in[12];
    const float* fo3_w = (const float*)d_in[13];
    const float* fo3_b = (const float*)d_in[14];
    const float* fc1_w = (const float*)d_in[15];
    const float* fc1_b = (const float*)d_in[16];
    const float* fc2_w = (const float*)d_in[17];
    const float* fc2_b = (const float*)d_in[18];
    const float* fc3_w = (const float*)d_in[19];
    const float* fc3_b = (const float*)d_in[20];

    char* ws = (char*)d_ws;
    float* out = (float*)d_out;

    prep_kernel<<<4837, 256, 0, stream>>>(x, fr1_w, fr1_b, fr2_w, fr2_b, fr3_w, fr3_b,
                                          fo1_w, fo1_b, fo2_w, fo2_b, fo3_w, fo3_b, ws);
    mlp3_kernel<8, false><<<B_ * 44, 256, 0, stream>>>(ws);   // edge MLP + aggregate
    mlp3_kernel<1, true ><<<600, 256, 0, stream>>>(ws);       // object MLP
    classifier_kernel<<<B_, 256, 0, stream>>>((const _Float16*)(ws + O_OFF),
                                              fc1_w, fc1_b, fc2_w, fc2_b, fc3_w, fc3_b, out);
}

// Round 5
// 111.781 us; speedup vs baseline: 9.6208x; 1.2437x over previous
//
#include <hip/hip_runtime.h>

#define N_   150
#define P_   16
#define DE_  14
#define DO_  10
#define NT_  5
#define B_   256
#define NRE  22350
#define H2_  25
#define HID_ 50
#define RPW  5              // receivers per wave

typedef float    f32x4 __attribute__((ext_vector_type(4)));
typedef _Float16 f16x8 __attribute__((ext_vector_type(8)));
typedef _Float16 f16x4 __attribute__((ext_vector_type(4)));

typedef f16x8 f16x8_a __attribute__((may_alias));
typedef f16x4 f16x4_a __attribute__((may_alias));
typedef int2  int2_a  __attribute__((may_alias));
typedef f32x4 f32x4_a __attribute__((may_alias));

// ---- ws layout (bytes) ----
#define EBAR_OFF 0u          // f32 [38400][16] (rows padded 14->16) = 2457600
#define O_OFF    2457600u    // f16 [38400][10]                      =  768000
#define XT_OFF   3225600u    // f16 [38400][16]                      = 1228800
#define W1E_OFF  4454400u    // f16 [64][32]
#define W1O_OFF  4458496u    // f16 [64][32]
#define W2E_OFF  4462592u    // f16 [32][64]
#define W2O_OFF  4466688u    // f16 [32][64]
#define W3E_OFF  4470784u    // f16 [16][32]
#define W3O_OFF  4471808u    // f16 [16][32]
#define B1E_OFF  4472832u    // f32 [64]
#define B1O_OFF  4473088u
#define B2E_OFF  4473344u    // f32 [32]
#define B2O_OFF  4473472u
#define B3E_OFF  4473600u    // f32 [16]
#define B3O_OFF  4473664u
// total 4473728 B

// ---------------------------------------------------------------------------
// prep: xT (fp16 transpose of x), padded fp16 weights, padded f32 biases.
// (No Ebar zeroing needed anymore: edge kernel writes every row exactly once.)
// ---------------------------------------------------------------------------
__global__ __launch_bounds__(256) void prep_kernel(
    const float* __restrict__ x,
    const float* __restrict__ fr1_w, const float* __restrict__ fr1_b,
    const float* __restrict__ fr2_w, const float* __restrict__ fr2_b,
    const float* __restrict__ fr3_w, const float* __restrict__ fr3_b,
    const float* __restrict__ fo1_w, const float* __restrict__ fo1_b,
    const float* __restrict__ fo2_w, const float* __restrict__ fo2_b,
    const float* __restrict__ fo3_w, const float* __restrict__ fo3_b,
    char* __restrict__ ws)
{
    int tid = blockIdx.x * 256 + threadIdx.x;
    if (tid < 614400) {                       // xT[b][n][p] = x[b][p][n]
        int b = tid / 2400; int rr = tid - b * 2400;
        int n = rr >> 4, p = rr & 15;
        ((_Float16*)(ws + XT_OFF))[tid] = (_Float16)x[b * 2400 + p * N_ + n];
        return;
    }
    int t = tid - 614400;
    if (t < 2048) { int n = t >> 5, k = t & 31;          // W1e [64][32]
        ((_Float16*)(ws + W1E_OFF))[t] = (_Float16)((n < 50) ? fr1_w[n * 32 + k] : 0.f); return; }
    t -= 2048;
    if (t < 2048) { int n = t >> 5, k = t & 31;          // W1o [64][32]
        ((_Float16*)(ws + W1O_OFF))[t] = (_Float16)((n < 50 && k < 30) ? fo1_w[n * 30 + k] : 0.f); return; }
    t -= 2048;
    if (t < 2048) { int n = t >> 6, k = t & 63;          // W2e [32][64]
        ((_Float16*)(ws + W2E_OFF))[t] = (_Float16)((n < 25 && k < 50) ? fr2_w[n * 50 + k] : 0.f); return; }
    t -= 2048;
    if (t < 2048) { int n = t >> 6, k = t & 63;          // W2o [32][64]
        ((_Float16*)(ws + W2O_OFF))[t] = (_Float16)((n < 25 && k < 50) ? fo2_w[n * 50 + k] : 0.f); return; }
    t -= 2048;
    if (t < 512) { int n = t >> 5, k = t & 31;           // W3e [16][32]
        ((_Float16*)(ws + W3E_OFF))[t] = (_Float16)((n < 14 && k < 25) ? fr3_w[n * 25 + k] : 0.f); return; }
    t -= 512;
    if (t < 512) { int n = t >> 5, k = t & 31;           // W3o [16][32]
        ((_Float16*)(ws + W3O_OFF))[t] = (_Float16)((n < 10 && k < 25) ? fo3_w[n * 25 + k] : 0.f); return; }
    t -= 512;
    if (t < 64) { ((float*)(ws + B1E_OFF))[t] = (t < 50) ? fr1_b[t] : 0.f; return; }
    t -= 64;
    if (t < 64) { ((float*)(ws + B1O_OFF))[t] = (t < 50) ? fo1_b[t] : 0.f; return; }
    t -= 64;
    if (t < 32) { ((float*)(ws + B2E_OFF))[t] = (t < 25) ? fr2_b[t] : 0.f; return; }
    t -= 32;
    if (t < 32) { ((float*)(ws + B2O_OFF))[t] = (t < 25) ? fo2_b[t] : 0.f; return; }
    t -= 32;
    if (t < 16) { ((float*)(ws + B3E_OFF))[t] = (t < 14) ? fr3_b[t] : 0.f; return; }
    t -= 16;
    if (t < 16) { ((float*)(ws + B3O_OFF))[t] = (t < 10) ? fo3_b[t] : 0.f; return; }
}

__device__ __forceinline__ unsigned pk2(float a, float b) {
    auto p = __builtin_amdgcn_cvt_pkrtz(a, b);   // __fp16 ext_vector(2)
    return __builtin_bit_cast(unsigned, p);
}
// relu on packed fp16 pair (1 VOP3P instead of 2 scalar v_max)
__device__ __forceinline__ unsigned pkmax0(unsigned x, unsigned z) {
    unsigned r;
    asm("v_pk_max_f16 %0, %1, %2" : "=v"(r) : "v"(x), "v"(z));
    return r;
}

// 16-lane-row sum via DPP row_ror (VALU pipe)
template<int CTRL>
__device__ __forceinline__ float dppadd(float v) {
    int s = __builtin_amdgcn_update_dpp(0, __builtin_bit_cast(int, v), CTRL, 0xF, 0xF, true);
    return v + __builtin_bit_cast(float, s);
}
__device__ __forceinline__ float dpp_sum16(float v) {
    v = dppadd<0x121>(v);
    v = dppadd<0x122>(v);
    v = dppadd<0x124>(v);
    v = dppadd<0x128>(v);
    return v;
}

// ---------------------------------------------------------------------------
// Edge kernel, sender-column formulation. One wave owns RPW receivers of one
// batch element. Per r: h1_pre = W1r*xr + b1 (4x mfma_16x16x16, B=broadcast),
// then 10 sender-tiles (cols = 16 consecutive senders):
//   L1: 4x mfma_16x16x16(W1s, xs, C=h1_pre) -> relu/pack -> LDS
//   L2: 2x b128 read, 4x mfma_16x16x32 -> relu/pack -> LDS
//   L3: 1x b128 read, 1x mfma_16x16x32(W3, h2, C=b3) -> relu -> register acc
// Sum over senders lives in registers; one dpp_sum16 + f32x4 store per r.
// No atomics. Wave-private double-buffered LDS, no barriers.
// ---------------------------------------------------------------------------
__global__ __launch_bounds__(256) void edge_kernel(char* __restrict__ ws)
{
    const _Float16* __restrict__ xT = (const _Float16*)(ws + XT_OFF);
    const _Float16* __restrict__ W1 = (const _Float16*)(ws + W1E_OFF);
    const _Float16* __restrict__ W2 = (const _Float16*)(ws + W2E_OFF);
    const _Float16* __restrict__ W3 = (const _Float16*)(ws + W3E_OFF);
    const float* __restrict__ b1 = (const float*)(ws + B1E_OFF);
    const float* __restrict__ b2 = (const float*)(ws + B2E_OFF);
    const float* __restrict__ b3 = (const float*)(ws + B3E_OFF);
    float* __restrict__ Ebar = (float*)(ws + EBAR_OFF);

    const int t = threadIdx.x, lane = t & 63, wid = t >> 6;
    const int e16 = lane & 15, g = lane >> 4;

    __shared__ __align__(16) char s_lds[4][6144];   // 2 x (h1 2KB + h2 1KB) per wave
    char* L = s_lds[wid];

    const int gw = blockIdx.x * 4 + wid;            // 0..7679
    const int b  = gw / 30;                         // 30 wave-slots per batch elem
    const int r0 = (gw - b * 30) * RPW;

    // A-frags (16x16x16: 4 f16, k=4g+j ; 16x16x32: 8 f16, k=8g+j)
    f16x4 A1r[4], A1s[4];
#pragma unroll
    for (int nt = 0; nt < 4; ++nt) {
        A1r[nt] = *(const f16x4*)&W1[(nt * 16 + e16) * 32 + g * 4];        // recv half k=0..15
        A1s[nt] = *(const f16x4*)&W1[(nt * 16 + e16) * 32 + 16 + g * 4];   // send half k=16..31
    }
    f16x8 A2f[2][2], A3f;
#pragma unroll
    for (int nt = 0; nt < 2; ++nt)
#pragma unroll
        for (int kt = 0; kt < 2; ++kt)
            A2f[nt][kt] = *(const f16x8*)&W2[(nt * 16 + e16) * 64 + kt * 32 + g * 8];
    A3f = *(const f16x8*)&W3[e16 * 32 + g * 8];

    f32x4 Cb1[4], Cb2[2], Cb3;
#pragma unroll
    for (int nt = 0; nt < 4; ++nt) Cb1[nt] = *(const f32x4*)&b1[nt * 16 + g * 4];
#pragma unroll
    for (int nt = 0; nt < 2; ++nt) Cb2[nt] = *(const f32x4*)&b2[nt * 16 + g * 4];
    Cb3 = *(const f32x4*)&b3[g * 4];

    const char* xTb = (const char*)xT + b * 4800;   // 150 rows * 32 B
    const int laneoff = e16 * 32 + g * 8;           // xs gather offset (b64, coalesced)
    const int wsub = (g >> 1) * 256 + e16 * 16 + 8 * (g & 1);  // LDS write sub-addr
    const int rsub = g * 256 + e16 * 16;                       // LDS read  sub-addr
    const unsigned zu = 0;

    for (int rr = 0; rr < RPW; ++rr) {
        const int r = r0 + rr;

        // h1_pre = W1r * xr + b1   (B = xr broadcast to all cols)
        f16x4 Bxr = *(const f16x4_a*)(xTb + r * 32 + g * 8);
        f32x4 H1P[4];
#pragma unroll
        for (int nt = 0; nt < 4; ++nt)
            H1P[nt] = __builtin_amdgcn_mfma_f32_16x16x16f16(A1r[nt], Bxr, Cb1[nt], 0, 0, 0);

        const int ktile = r >> 4, klane = r & 15;
        float ac0 = 0.f, ac1 = 0.f, ac2 = 0.f, ac3 = 0.f;

#pragma unroll 2
        for (int tile = 0; tile < 10; ++tile) {
            char* h1b = L + (tile & 1) * 3072;
            char* h2b = h1b + 2048;

            // xs B-frag: col = sender tile*16+e16, k = 4g+j
            f16x4 Bxs = *(const f16x4_a*)(xTb + tile * 512 + laneoff);

            // ---- L1 (sender half-K), C = h1_pre ----
#pragma unroll
            for (int nt = 0; nt < 4; ++nt) {
                f32x4 d1 = __builtin_amdgcn_mfma_f32_16x16x16f16(A1s[nt], Bxs, H1P[nt], 0, 0, 0);
                int2 pw;
                pw.x = (int)pkmax0(pk2(d1[0], d1[1]), zu);
                pw.y = (int)pkmax0(pk2(d1[2], d1[3]), zu);
                *(int2_a*)(h1b + nt * 512 + wsub) = pw;
            }

            // ---- L2: K=64 in 2 ksteps ----
            f16x8 B2a = *(const f16x8_a*)(h1b + rsub);
            f16x8 B2b = *(const f16x8_a*)(h1b + 1024 + rsub);
#pragma unroll
            for (int nt = 0; nt < 2; ++nt) {
                f32x4 d2 = __builtin_amdgcn_mfma_f32_16x16x32_f16(A2f[nt][0], B2a, Cb2[nt], 0, 0, 0);
                d2 = __builtin_amdgcn_mfma_f32_16x16x32_f16(A2f[nt][1], B2b, d2, 0, 0, 0);
                int2 pw;
                pw.x = (int)pkmax0(pk2(d2[0], d2[1]), zu);
                pw.y = (int)pkmax0(pk2(d2[2], d2[3]), zu);
                *(int2_a*)(h2b + nt * 512 + wsub) = pw;
            }

            // ---- L3 ----
            f16x8 B3f = *(const f16x8_a*)(h2b + rsub);
            f32x4 d3 = __builtin_amdgcn_mfma_f32_16x16x32_f16(A3f, B3f, Cb3, 0, 0, 0);

            float v0 = fmaxf(d3[0], 0.f), v1 = fmaxf(d3[1], 0.f);
            float v2 = fmaxf(d3[2], 0.f), v3 = fmaxf(d3[3], 0.f);
            if (tile == ktile || tile == 9) {               // wave-uniform branch
                bool kill = (tile == ktile && e16 == klane) || (tile == 9 && e16 >= 6);
                if (kill) { v0 = 0.f; v1 = 0.f; v2 = 0.f; v3 = 0.f; }
            }
            ac0 += v0; ac1 += v1; ac2 += v2; ac3 += v3;
        }

        // reduce over the 16 sender-cols, write Ebar row (d = 4g+reg)
        ac0 = dpp_sum16(ac0); ac1 = dpp_sum16(ac1);
        ac2 = dpp_sum16(ac2); ac3 = dpp_sum16(ac3);
        if (e16 == 0) {
            f32x4 o = { ac0, ac1, ac2, ac3 };
            *(f32x4_a*)&Ebar[(b * 150 + r) * 16 + g * 4] = o;
        }
    }
}

// ---------------------------------------------------------------------------
// Object MLP (unchanged from round 4): cols = 16 node-rows, 3-layer MFMA chain
// ---------------------------------------------------------------------------
__global__ __launch_bounds__(256) void obj_kernel(char* __restrict__ ws)
{
    const _Float16* __restrict__ xT = (const _Float16*)(ws + XT_OFF);
    const _Float16* __restrict__ W1 = (const _Float16*)(ws + W1O_OFF);
    const _Float16* __restrict__ W2 = (const _Float16*)(ws + W2O_OFF);
    const _Float16* __restrict__ W3 = (const _Float16*)(ws + W3O_OFF);
    const float* __restrict__ b1 = (const float*)(ws + B1O_OFF);
    const float* __restrict__ b2 = (const float*)(ws + B2O_OFF);
    const float* __restrict__ b3 = (const float*)(ws + B3O_OFF);
    const float* __restrict__ Ebar = (const float*)(ws + EBAR_OFF);
    _Float16* __restrict__ O = (_Float16*)(ws + O_OFF);

    const int t = threadIdx.x, lane = t & 63, wid = t >> 6;
    const int e16 = lane & 15, g = lane >> 4;

    __shared__ __align__(16) char s_lds[4][3072];
    char* ldsw = s_lds[wid];
    const int wsub = (g >> 1) * 256 + e16 * 16 + (g & 1) * 8;
    char*       h1w = ldsw + wsub;
    char*       h2w = ldsw + 2048 + wsub;
    const int rsub = g * 256 + e16 * 16;
    const char* h1r = ldsw + rsub;
    const char* h2r = ldsw + 2048 + rsub;

    f16x8 A1[4], A2[2][2], A3;
#pragma unroll
    for (int nt = 0; nt < 4; ++nt)
        A1[nt] = *(const f16x8*)&W1[(nt * 16 + e16) * 32 + g * 8];
#pragma unroll
    for (int nt = 0; nt < 2; ++nt)
#pragma unroll
        for (int kt = 0; kt < 2; ++kt)
            A2[nt][kt] = *(const f16x8*)&W2[(nt * 16 + e16) * 64 + kt * 32 + g * 8];
    A3 = *(const f16x8*)&W3[e16 * 32 + g * 8];

    f32x4 C1[4], C2[2];
#pragma unroll
    for (int nt = 0; nt < 4; ++nt) C1[nt] = *(const f32x4*)&b1[nt * 16 + g * 4];
#pragma unroll
    for (int nt = 0; nt < 2; ++nt) C2[nt] = *(const f32x4*)&b2[nt * 16 + g * 4];
    const float b3v = b3[e16];
    const f32x4 C3 = { b3v, b3v, b3v, b3v };
    const unsigned zu = 0;

    const int tile = blockIdx.x * 4 + wid;   // 600 blocks * 4 waves = 2400 tiles
    const int m = tile * 16 + e16;

    f16x8 Bf;
    if (g < 2) {
        Bf = *(const f16x8*)&xT[m * 16 + g * 8];
    } else {
        const float* ep = &Ebar[m * 16 + (g & 1) * 8];
        f32x4 u0 = *(const f32x4_a*)ep;
        f32x4 u1 = *(const f32x4_a*)(ep + 4);
        uint4 uw;
        uw.x = pk2(u0[0], u0[1]); uw.y = pk2(u0[2], u0[3]);
        uw.z = pk2(u1[0], u1[1]); uw.w = pk2(u1[2], u1[3]);
        Bf = __builtin_bit_cast(f16x8, uw);
    }

#pragma unroll
    for (int nt = 0; nt < 4; ++nt) {
        f32x4 a = __builtin_amdgcn_mfma_f32_16x16x32_f16(A1[nt], Bf, C1[nt], 0, 0, 0);
        int2 pw;
        pw.x = (int)pkmax0(pk2(a[0], a[1]), zu);
        pw.y = (int)pkmax0(pk2(a[2], a[3]), zu);
        *(int2_a*)(h1w + nt * 512) = pw;
    }
    f16x8 B2a = *(const f16x8_a*)(h1r);
    f16x8 B2b = *(const f16x8_a*)(h1r + 1024);
#pragma unroll
    for (int nt = 0; nt < 2; ++nt) {
        f32x4 a = __builtin_amdgcn_mfma_f32_16x16x32_f16(A2[nt][0], B2a, C2[nt], 0, 0, 0);
        a = __builtin_amdgcn_mfma_f32_16x16x32_f16(A2[nt][1], B2b, a, 0, 0, 0);
        int2 pw;
        pw.x = (int)pkmax0(pk2(a[0], a[1]), zu);
        pw.y = (int)pkmax0(pk2(a[2], a[3]), zu);
        *(int2_a*)(h2w + nt * 512) = pw;
    }
    f16x8 Af3 = *(const f16x8_a*)(h2r);
    f32x4 acc3 = __builtin_amdgcn_mfma_f32_16x16x32_f16(Af3, A3, C3, 0, 0, 0);

    if (e16 < DO_) {
#pragma unroll
        for (int v = 0; v < 4; ++v)
            O[(tile * 16 + g * 4 + v) * DO_ + e16] = (_Float16)fmaxf(acc3[v], 0.f);
    }
}

// ---------------------------------------------------------------------------
// classifier fc1/fc2/fc3 (fp32), one block per batch element; O read as fp16
// ---------------------------------------------------------------------------
__global__ __launch_bounds__(256) void classifier_kernel(
    const _Float16* __restrict__ O,
    const float* __restrict__ fc1_w, const float* __restrict__ fc1_b,
    const float* __restrict__ fc2_w, const float* __restrict__ fc2_b,
    const float* __restrict__ fc3_w, const float* __restrict__ fc3_b,
    float* __restrict__ out)
{
    __shared__ float s_o[N_ * DO_];
    __shared__ float s_part[4][HID_];
    __shared__ float s_h1[HID_];
    __shared__ float s_h2[H2_];

    const int b = blockIdx.x;
    const int t = threadIdx.x;
    const int lane = t & 63, w = t >> 6;

    const _Float16* Ob = O + b * (N_ * DO_);
    for (int k = t; k < N_ * DO_; k += 256) s_o[k] = (float)Ob[k];
    __syncthreads();

    float acc[HID_];
#pragma unroll
    for (int i = 0; i < HID_; ++i) acc[i] = 0.0f;

    for (int kb = 0; kb < N_ * DO_; kb += 256) {
        int k = kb + t;
        if (k < N_ * DO_) {
            float o = s_o[k];
#pragma unroll
            for (int i = 0; i < HID_; ++i)
                acc[i] = fmaf(fc1_w[i * (N_ * DO_) + k], o, acc[i]);
        }
    }

#pragma unroll
    for (int i = 0; i < HID_; ++i) {
        float v = acc[i];
#pragma unroll
        for (int off = 32; off >= 1; off >>= 1) v += __shfl_xor(v, off);
        if (lane == i) s_part[w][i] = v;
    }
    __syncthreads();

    if (t < HID_) {
        float v = s_part[0][t] + s_part[1][t] + s_part[2][t] + s_part[3][t] + fc1_b[t];
        s_h1[t] = fmaxf(v, 0.0f);
    }
    __syncthreads();
    if (t < H2_) {
        float a = fc2_b[t];
#pragma unroll
        for (int k = 0; k < HID_; ++k) a = fmaf(fc2_w[t * HID_ + k], s_h1[k], a);
        s_h2[t] = fmaxf(a, 0.0f);
    }
    __syncthreads();
    if (t < NT_) {
        float a = fc3_b[t];
#pragma unroll
        for (int k = 0; k < H2_; ++k) a = fmaf(fc3_w[t * H2_ + k], s_h2[k], a);
        out[b * NT_ + t] = a;
    }
}

extern "C" void kernel_launch(void* const* d_in, const int* in_sizes, int n_in,
                              void* d_out, int out_size, void* d_ws, size_t ws_size,
                              hipStream_t stream) {
    const float* x     = (const float*)d_in[0];
    const float* fr1_w = (const float*)d_in[3];
    const float* fr1_b = (const float*)d_in[4];
    const float* fr2_w = (const float*)d_in[5];
    const float* fr2_b = (const float*)d_in[6];
    const float* fr3_w = (const float*)d_in[7];
    const float* fr3_b = (const float*)d_in[8];
    const float* fo1_w = (const float*)d_in[9];
    const float* fo1_b = (const float*)d_in[10];
    const float* fo2_w = (const float*)d_in[11];
    const float* fo2_b = (const float*)d_in[12];
    const float* fo3_w = (const float*)d_in[13];
    const float* fo3_b = (const float*)d_in[14];
    const float* fc1_w = (const float*)d_in[15];
    const float* fc1_b = (const float*)d_in[16];
    const float* fc2_w = (const float*)d_in[17];
    const float* fc2_b = (const float*)d_in[18];
    const float* fc3_w = (const float*)d_in[19];
    const float* fc3_b = (const float*)d_in[20];

    char* ws = (char*)d_ws;
    float* out = (float*)d_out;

    prep_kernel<<<2437, 256, 0, stream>>>(x, fr1_w, fr1_b, fr2_w, fr2_b, fr3_w, fr3_b,
                                          fo1_w, fo1_b, fo2_w, fo2_b, fo3_w, fo3_b, ws);
    edge_kernel<<<1920, 256, 0, stream>>>(ws);                // 7680 waves = 256 b x 30
    obj_kernel<<<600, 256, 0, stream>>>(ws);
    classifier_kernel<<<B_, 256, 0, stream>>>((const _Float16*)(ws + O_OFF),
                                              fc1_w, fc1_b, fc2_w, fc2_b, fc3_w, fc3_b, out);
}